// Round 5
// baseline (9545.586 us; speedup 1.0000x reference)
//
#include <hip/hip_runtime.h>
#include <math.h>

#define TPB 256

// ---- LDS layout (float word offsets) ----
// Weight rows padded: stride 84 (mod 32 = 20) and 132 (mod 32 = 4) give
// conflict-optimal per-lane ds_read_b128 (8 words/bank per wave access).
#define W0_OFF 0        // 128 rows x 84 (80 used)
#define W0_STR 84
#define W1_OFF 10752    // 128 rows x 132 (128 used)
#define W1_STR 132
#define W2_OFF 27648    // 64 rows x 132 (128 used)
#define W2_STR 132
#define B0_OFF 36096    // 128
#define B1_OFF 36224    // 128
#define B2_OFF 36352    // 64
#define Z_OFF  36416    // 8 x 84   (z = [y(64), u(16)]) — wave-private rows
#define Z_STR  84
#define HA_OFF 37088    // 8 x 128  h1 — wave-private rows
#define HB_OFF 38112    // 8 x 128  h2 — wave-private rows
#define H_STR  128
#define SM_WORDS 39136  // 156.5 KB
#define SM_BYTES (SM_WORDS * 4)

__device__ __forceinline__ float4 ld4(const float* p) {
  return *reinterpret_cast<const float4*>(p);
}

// One MLP eval for TWO elements owned by this wave. Entirely wave-private:
// z/h rows belong to this wave, so ds_write -> ds_read ordering within the
// wave (lgkmcnt) is sufficient — NO __syncthreads anywhere.
// Each output is a single ascending fmaf chain from its bias (bit-exact,
// identical order to the round-3 absmax=0.0 kernel).
__device__ __forceinline__ void eval_f2(const float* __restrict__ sm,
                                        float* hA1, float* hB1,
                                        float* hA2, float* hB2,
                                        const float* zA, const float* zB,
                                        int lane, float& kA, float& kB)
{
  // ---- L1: h1 = tanh(W0 z + b0), fan_in 80; features lane, lane+64 ----
  {
    float a00 = sm[B0_OFF + lane];        // (j=lane,   elA)
    float a01 = a00;                      // (j=lane,   elB)
    float a10 = sm[B0_OFF + lane + 64];   // (j=lane+64, elA)
    float a11 = a10;                      // (j=lane+64, elB)
    const float* w0a = sm + W0_OFF + lane * W0_STR;
    const float* w0b = sm + W0_OFF + (lane + 64) * W0_STR;
#pragma unroll
    for (int i4 = 0; i4 < 20; ++i4) {
      float4 wa = ld4(w0a + i4 * 4);
      float4 wb = ld4(w0b + i4 * 4);
      float4 za = ld4(zA + i4 * 4);
      float4 zb = ld4(zB + i4 * 4);
      a00 = fmaf(wa.x, za.x, a00); a00 = fmaf(wa.y, za.y, a00);
      a00 = fmaf(wa.z, za.z, a00); a00 = fmaf(wa.w, za.w, a00);
      a01 = fmaf(wa.x, zb.x, a01); a01 = fmaf(wa.y, zb.y, a01);
      a01 = fmaf(wa.z, zb.z, a01); a01 = fmaf(wa.w, zb.w, a01);
      a10 = fmaf(wb.x, za.x, a10); a10 = fmaf(wb.y, za.y, a10);
      a10 = fmaf(wb.z, za.z, a10); a10 = fmaf(wb.w, za.w, a10);
      a11 = fmaf(wb.x, zb.x, a11); a11 = fmaf(wb.y, zb.y, a11);
      a11 = fmaf(wb.z, zb.z, a11); a11 = fmaf(wb.w, zb.w, a11);
    }
    hA1[lane]      = tanhf(a00);
    hB1[lane]      = tanhf(a01);
    hA1[lane + 64] = tanhf(a10);
    hB1[lane + 64] = tanhf(a11);
  }

  // ---- L2: h2 = tanh(W1 h1 + b1), fan_in 128 ----
  {
    float a00 = sm[B1_OFF + lane];
    float a01 = a00;
    float a10 = sm[B1_OFF + lane + 64];
    float a11 = a10;
    const float* w1a = sm + W1_OFF + lane * W1_STR;
    const float* w1b = sm + W1_OFF + (lane + 64) * W1_STR;
#pragma unroll
    for (int i4 = 0; i4 < 32; ++i4) {
      float4 wa = ld4(w1a + i4 * 4);
      float4 wb = ld4(w1b + i4 * 4);
      float4 za = ld4(hA1 + i4 * 4);
      float4 zb = ld4(hB1 + i4 * 4);
      a00 = fmaf(wa.x, za.x, a00); a00 = fmaf(wa.y, za.y, a00);
      a00 = fmaf(wa.z, za.z, a00); a00 = fmaf(wa.w, za.w, a00);
      a01 = fmaf(wa.x, zb.x, a01); a01 = fmaf(wa.y, zb.y, a01);
      a01 = fmaf(wa.z, zb.z, a01); a01 = fmaf(wa.w, zb.w, a01);
      a10 = fmaf(wb.x, za.x, a10); a10 = fmaf(wb.y, za.y, a10);
      a10 = fmaf(wb.z, za.z, a10); a10 = fmaf(wb.w, za.w, a10);
      a11 = fmaf(wb.x, zb.x, a11); a11 = fmaf(wb.y, zb.y, a11);
      a11 = fmaf(wb.z, zb.z, a11); a11 = fmaf(wb.w, zb.w, a11);
    }
    hA2[lane]      = tanhf(a00);
    hB2[lane]      = tanhf(a01);
    hA2[lane + 64] = tanhf(a10);
    hB2[lane + 64] = tanhf(a11);
  }

  // ---- L3: k = W2 h2 + b2 (no tanh); output dim j = lane ----
  {
    float aA = sm[B2_OFF + lane];
    float aB = aA;
    const float* w2 = sm + W2_OFF + lane * W2_STR;
#pragma unroll
    for (int i4 = 0; i4 < 32; ++i4) {
      float4 w  = ld4(w2 + i4 * 4);
      float4 za = ld4(hA2 + i4 * 4);
      float4 zb = ld4(hB2 + i4 * 4);
      aA = fmaf(w.x, za.x, aA); aA = fmaf(w.y, za.y, aA);
      aA = fmaf(w.z, za.z, aA); aA = fmaf(w.w, za.w, aA);
      aB = fmaf(w.x, zb.x, aB); aB = fmaf(w.y, zb.y, aB);
      aB = fmaf(w.z, zb.z, aB); aB = fmaf(w.w, zb.w, aB);
    }
    kA = aA; kB = aB;
  }
}

__global__ __launch_bounds__(TPB, 1)
void ode_solver(const float* __restrict__ x0, const float* __restrict__ u,
                const float* __restrict__ t0p, const float* __restrict__ t1p,
                const float* __restrict__ W0g, const float* __restrict__ b0g,
                const float* __restrict__ W1g, const float* __restrict__ b1g,
                const float* __restrict__ W2g, const float* __restrict__ b2g,
                float* __restrict__ out, int B)
{
  extern __shared__ float sm[];
  const int tid = threadIdx.x;
  const int blk = blockIdx.x;

  // ---- stage weights into LDS (one-time per block) ----
  for (int idx = tid; idx < 128 * 80; idx += TPB) {
    int j = idx / 80, i = idx - j * 80;
    sm[W0_OFF + j * W0_STR + i] = W0g[idx];
  }
  for (int idx = tid; idx < 128 * 128; idx += TPB) {
    int j = idx >> 7, i = idx & 127;
    sm[W1_OFF + j * W1_STR + i] = W1g[idx];
  }
  for (int idx = tid; idx < 64 * 128; idx += TPB) {
    int j = idx >> 7, i = idx & 127;
    sm[W2_OFF + j * W2_STR + i] = W2g[idx];
  }
  if (tid < 128) { sm[B0_OFF + tid] = b0g[tid]; sm[B1_OFF + tid] = b1g[tid]; }
  if (tid < 64)  { sm[B2_OFF + tid] = b2g[tid]; }
  if (tid < 128) {          // u occupies z[64..79] for 8 elements
    int e = tid >> 4, c = tid & 15;
    sm[Z_OFF + e * Z_STR + 64 + c] = u[(blk * 8 + e) * 16 + c];
  }

  const int wv   = tid >> 6;        // wave 0..3
  const int lane = tid & 63;        // state dim / feature base
  const int eA = 2 * wv, eB = 2 * wv + 1;
  const int geA = blk * 8 + eA, geB = blk * 8 + eB;

  float yA = x0[geA * 64 + lane];
  float yB = x0[geB * 64 + lane];
  const float t1  = *t1p;
  const float t1m = t1 - 1e-12f;    // matches XLA: f32(1.0 - 1e-12) == 1.0f
  float tA = *t0p, tB = tA;
  float dtA = (float)(60.0 * (1.0 / 3600.0)), dtB = dtA;
  int nstA = 0, nstB = 0;

  // DOPRI5 coefficients (f64 literals rounded to f32, as XLA does)
  constexpr float cA21 = (float)0.161;
  constexpr float cA31 = (float)-0.008480655492356989, cA32 = (float)0.335480655492357;
  constexpr float cA41 = (float)2.8971530571054935,  cA42 = (float)-6.359448489975075,  cA43 = (float)4.3622954328695815;
  constexpr float cA51 = (float)5.325864828439257,   cA52 = (float)-11.748883564062828, cA53 = (float)7.4955393428898365, cA54 = (float)-0.09249506636175525;
  constexpr float cA61 = (float)5.86145544294642,    cA62 = (float)-12.92096931784711,  cA63 = (float)8.159367898576159,  cA64 = (float)-0.071584973281401, cA65 = (float)-0.028269050394068383;
  constexpr float cB1 = (float)0.09646076681806523,  cB2 = (float)0.01, cB3 = (float)0.4798896504144996;
  constexpr float cB4 = (float)1.379008574103742,    cB5 = (float)-3.290069515436081, cB6 = (float)2.324710524099774;
  constexpr float cE1 = (float)-0.001780011052226,   cE2 = (float)-0.000816434459657, cE3 = (float)0.007880878010262;
  constexpr float cE4 = (float)-0.144711007173263,   cE5 = (float)0.582357165452555,  cE6 = (float)-0.458082105929187;
  constexpr float cE7 = (float)(-1.0 / 66.0);

  __syncthreads();   // the ONLY barrier: weights/u staged

  float* zA  = sm + Z_OFF + eA * Z_STR;
  float* zB  = sm + Z_OFF + eB * Z_STR;
  float* hA1 = sm + HA_OFF + eA * H_STR;
  float* hB1 = sm + HA_OFF + eB * H_STR;
  float* hA2 = sm + HB_OFF + eA * H_STR;
  float* hB2 = sm + HB_OFF + eB * H_STR;

  for (int it = 0; it < 128; ++it) {
    const bool doneA = (tA >= t1m);
    const bool doneB = (tB >= t1m);
    if (doneA && doneB) break;      // wave-uniform (t is lane-uniform)

    const float dA = fminf(dtA, t1 - tA);
    const float dB = fminf(dtB, t1 - tB);

    float k1A, k1B, k2A, k2B, k3A, k3B, k4A, k4B, k5A, k5B, k6A, k6B, k7A, k7B;

    zA[lane] = yA;  zB[lane] = yB;
    eval_f2(sm, hA1, hB1, hA2, hB2, zA, zB, lane, k1A, k1B);

    zA[lane] = yA + dA * (cA21 * k1A);
    zB[lane] = yB + dB * (cA21 * k1B);
    eval_f2(sm, hA1, hB1, hA2, hB2, zA, zB, lane, k2A, k2B);

    zA[lane] = yA + dA * (cA31 * k1A + cA32 * k2A);
    zB[lane] = yB + dB * (cA31 * k1B + cA32 * k2B);
    eval_f2(sm, hA1, hB1, hA2, hB2, zA, zB, lane, k3A, k3B);

    zA[lane] = yA + dA * (cA41 * k1A + cA42 * k2A + cA43 * k3A);
    zB[lane] = yB + dB * (cA41 * k1B + cA42 * k2B + cA43 * k3B);
    eval_f2(sm, hA1, hB1, hA2, hB2, zA, zB, lane, k4A, k4B);

    zA[lane] = yA + dA * (cA51 * k1A + cA52 * k2A + cA53 * k3A + cA54 * k4A);
    zB[lane] = yB + dB * (cA51 * k1B + cA52 * k2B + cA53 * k3B + cA54 * k4B);
    eval_f2(sm, hA1, hB1, hA2, hB2, zA, zB, lane, k5A, k5B);

    zA[lane] = yA + dA * (cA61 * k1A + cA62 * k2A + cA63 * k3A + cA64 * k4A + cA65 * k5A);
    zB[lane] = yB + dB * (cA61 * k1B + cA62 * k2B + cA63 * k3B + cA64 * k4B + cA65 * k5B);
    eval_f2(sm, hA1, hB1, hA2, hB2, zA, zB, lane, k6A, k6B);

    const float y5A = yA + dA * (cB1 * k1A + cB2 * k2A + cB3 * k3A + cB4 * k4A + cB5 * k5A + cB6 * k6A);
    const float y5B = yB + dB * (cB1 * k1B + cB2 * k2B + cB3 * k3B + cB4 * k4B + cB5 * k5B + cB6 * k6B);
    zA[lane] = y5A;  zB[lane] = y5B;
    eval_f2(sm, hA1, hB1, hA2, hB2, zA, zB, lane, k7A, k7B);

    const float errA = dA * (cE1 * k1A + cE2 * k2A + cE3 * k3A + cE4 * k4A + cE5 * k5A + cE6 * k6A + cE7 * k7A);
    const float errB = dB * (cE1 * k1B + cE2 * k2B + cE3 * k3B + cE4 * k4B + cE5 * k5B + cE6 * k6B + cE7 * k7B);
    const float scA = 1.4e-8f + 1.4e-8f * fmaxf(fabsf(yA), fabsf(y5A));
    const float scB = 1.4e-8f + 1.4e-8f * fmaxf(fabsf(yB), fabsf(y5B));
    const float rA = errA / scA;
    const float rB = errB / scB;
    float s2A = rA * rA;
    float s2B = rB * rB;
#pragma unroll
    for (int m = 1; m < 64; m <<= 1) {
      s2A += __shfl_xor(s2A, m);
      s2B += __shfl_xor(s2B, m);
    }
    const float enA = sqrtf(s2A * (1.0f / 64.0f));
    const float enB = sqrtf(s2B * (1.0f / 64.0f));

    float facA = 0.9f * powf(fmaxf(enA, 1e-16f), -0.2f);
    float facB = 0.9f * powf(fmaxf(enB, 1e-16f), -0.2f);
    facA = fminf(10.0f, fmaxf(0.1f, facA));
    facB = fminf(10.0f, fmaxf(0.1f, facB));

    const bool stepA = (enA <= 1.0f) && !doneA;
    const bool stepB = (enB <= 1.0f) && !doneB;
    if (stepA) { tA = tA + dA; yA = y5A; }
    if (stepB) { tB = tB + dB; yB = y5B; }
    if (!doneA) dtA = dA * facA;
    if (!doneB) dtB = dB * facB;
    nstA += doneA ? 0 : 1;
    nstB += doneB ? 0 : 1;
  }

  // ---- outputs: y (B x 64) then nsteps (B) as float ----
  out[geA * 64 + lane] = yA;
  out[geB * 64 + lane] = yB;
  if (lane == 0) {
    out[B * 64 + geA] = (float)nstA;
    out[B * 64 + geB] = (float)nstB;
  }
}

extern "C" void kernel_launch(void* const* d_in, const int* in_sizes, int n_in,
                              void* d_out, int out_size, void* d_ws, size_t ws_size,
                              hipStream_t stream) {
  const float* x0 = (const float*)d_in[0];
  const float* u  = (const float*)d_in[1];
  const float* t0 = (const float*)d_in[2];
  const float* t1 = (const float*)d_in[3];
  const float* W0 = (const float*)d_in[4];
  const float* b0 = (const float*)d_in[5];
  const float* W1 = (const float*)d_in[6];
  const float* b1 = (const float*)d_in[7];
  const float* W2 = (const float*)d_in[8];
  const float* b2 = (const float*)d_in[9];
  float* out = (float*)d_out;

  const int B = in_sizes[0] / 64;   // 1024
  const int nblk = B / 8;           // 8 elements per block (2 per wave), 128 blocks

  (void)hipFuncSetAttribute((const void*)ode_solver,
                            hipFuncAttributeMaxDynamicSharedMemorySize, SM_BYTES);
  ode_solver<<<nblk, TPB, SM_BYTES, stream>>>(x0, u, t0, t1, W0, b0, W1, b1, W2, b2, out, B);
}

// Round 8
// 6249.110 us; speedup vs baseline: 1.5275x; 1.5275x over previous
//
#include <hip/hip_runtime.h>
#include <math.h>

#define TPB 128

// ---- LDS layout (float word offsets) ----
// Weight rows padded: stride 84 (mod 32 = 20) and 132 (mod 32 = 4) give
// conflict-optimal per-lane ds_read_b128.
#define W0_OFF 0        // 128 rows x 84 (80 used)
#define W0_STR 84
#define W1_OFF 10752    // 128 rows x 132 (128 used)
#define W1_STR 132
#define W2_OFF 27648    // 64 rows x 132 (128 used)
#define W2_STR 132
#define B0_OFF 36096    // 128
#define B1_OFF 36224    // 128
#define B2_OFF 36352    // 64
#define Z_OFF  36416    // 4 x 84   (z = [y(64), u(16)]) — wave-private rows
#define Z_STR  84
#define HA_OFF 36752    // 4 x 128  h1 — wave-private rows
#define HB_OFF 37264    // 4 x 128  h2 — wave-private rows
#define H_STR  128
#define SM_WORDS 37776  // 151.1 KB -> 1 block/CU
#define SM_BYTES (SM_WORDS * 4)

__device__ __forceinline__ float4 ld4(const float* p) {
  return *reinterpret_cast<const float4*>(p);
}

// MLP eval for the TWO elements owned by this wave. Wave-private z/h rows:
// ds_write->ds_read ordering within a wave needs no __syncthreads.
// Every output is one ascending fmaf chain from its bias (bit-exact, same
// order as the round-3/5 absmax=0.0 kernels). Outer loops carry
// "#pragma unroll 1" so transient in-flight loads stay <= 32 float4
// (the round-5 spill was full-unroll hoisting ~128 float4 loads).
__device__ __forceinline__ void eval_f2(const float* __restrict__ sm,
                                        float* hA1, float* hB1,
                                        float* hA2, float* hB2,
                                        const float* zA, const float* zB,
                                        int lane, float& kA, float& kB)
{
  // ---- L1: h1 = tanh(W0 z + b0), fan_in 80; features lane, lane+64 ----
  {
    float a00 = sm[B0_OFF + lane];
    float a01 = a00;
    float a10 = sm[B0_OFF + lane + 64];
    float a11 = a10;
    const float* w0a = sm + W0_OFF + lane * W0_STR;
    const float* w0b = sm + W0_OFF + (lane + 64) * W0_STR;
#pragma unroll 1
    for (int c = 0; c < 4; ++c) {
#pragma unroll
      for (int q = 0; q < 5; ++q) {
        const int i4 = c * 5 + q;
        float4 wa = ld4(w0a + i4 * 4);
        float4 wb = ld4(w0b + i4 * 4);
        float4 za = ld4(zA + i4 * 4);
        float4 zb = ld4(zB + i4 * 4);
        a00 = fmaf(wa.x, za.x, a00); a00 = fmaf(wa.y, za.y, a00);
        a00 = fmaf(wa.z, za.z, a00); a00 = fmaf(wa.w, za.w, a00);
        a01 = fmaf(wa.x, zb.x, a01); a01 = fmaf(wa.y, zb.y, a01);
        a01 = fmaf(wa.z, zb.z, a01); a01 = fmaf(wa.w, zb.w, a01);
        a10 = fmaf(wb.x, za.x, a10); a10 = fmaf(wb.y, za.y, a10);
        a10 = fmaf(wb.z, za.z, a10); a10 = fmaf(wb.w, za.w, a10);
        a11 = fmaf(wb.x, zb.x, a11); a11 = fmaf(wb.y, zb.y, a11);
        a11 = fmaf(wb.z, zb.z, a11); a11 = fmaf(wb.w, zb.w, a11);
      }
    }
    hA1[lane]      = tanhf(a00);
    hB1[lane]      = tanhf(a01);
    hA1[lane + 64] = tanhf(a10);
    hB1[lane + 64] = tanhf(a11);
  }

  // ---- L2: h2 = tanh(W1 h1 + b1), fan_in 128 ----
  {
    float a00 = sm[B1_OFF + lane];
    float a01 = a00;
    float a10 = sm[B1_OFF + lane + 64];
    float a11 = a10;
    const float* w1a = sm + W1_OFF + lane * W1_STR;
    const float* w1b = sm + W1_OFF + (lane + 64) * W1_STR;
#pragma unroll 1
    for (int c = 0; c < 4; ++c) {
#pragma unroll
      for (int q = 0; q < 8; ++q) {
        const int i4 = c * 8 + q;
        float4 wa = ld4(w1a + i4 * 4);
        float4 wb = ld4(w1b + i4 * 4);
        float4 za = ld4(hA1 + i4 * 4);
        float4 zb = ld4(hB1 + i4 * 4);
        a00 = fmaf(wa.x, za.x, a00); a00 = fmaf(wa.y, za.y, a00);
        a00 = fmaf(wa.z, za.z, a00); a00 = fmaf(wa.w, za.w, a00);
        a01 = fmaf(wa.x, zb.x, a01); a01 = fmaf(wa.y, zb.y, a01);
        a01 = fmaf(wa.z, zb.z, a01); a01 = fmaf(wa.w, zb.w, a01);
        a10 = fmaf(wb.x, za.x, a10); a10 = fmaf(wb.y, za.y, a10);
        a10 = fmaf(wb.z, za.z, a10); a10 = fmaf(wb.w, za.w, a10);
        a11 = fmaf(wb.x, zb.x, a11); a11 = fmaf(wb.y, zb.y, a11);
        a11 = fmaf(wb.z, zb.z, a11); a11 = fmaf(wb.w, zb.w, a11);
      }
    }
    hA2[lane]      = tanhf(a00);
    hB2[lane]      = tanhf(a01);
    hA2[lane + 64] = tanhf(a10);
    hB2[lane + 64] = tanhf(a11);
  }

  // ---- L3: k = W2 h2 + b2 (no tanh); output dim j = lane ----
  {
    float aA = sm[B2_OFF + lane];
    float aB = aA;
    const float* w2 = sm + W2_OFF + lane * W2_STR;
#pragma unroll 1
    for (int c = 0; c < 4; ++c) {
#pragma unroll
      for (int q = 0; q < 8; ++q) {
        const int i4 = c * 8 + q;
        float4 w  = ld4(w2 + i4 * 4);
        float4 za = ld4(hA2 + i4 * 4);
        float4 zb = ld4(hB2 + i4 * 4);
        aA = fmaf(w.x, za.x, aA); aA = fmaf(w.y, za.y, aA);
        aA = fmaf(w.z, za.z, aA); aA = fmaf(w.w, za.w, aA);
        aB = fmaf(w.x, zb.x, aB); aB = fmaf(w.y, zb.y, aB);
        aB = fmaf(w.z, zb.z, aB); aB = fmaf(w.w, zb.w, aB);
      }
    }
    kA = aA; kB = aB;
  }
}

__global__ __launch_bounds__(TPB, 2)
void ode_solver(const float* __restrict__ x0, const float* __restrict__ u,
                const float* __restrict__ t0p, const float* __restrict__ t1p,
                const float* __restrict__ W0g, const float* __restrict__ b0g,
                const float* __restrict__ W1g, const float* __restrict__ b1g,
                const float* __restrict__ W2g, const float* __restrict__ b2g,
                float* __restrict__ out, int B)
{
  extern __shared__ float sm[];
  const int tid = threadIdx.x;
  const int blk = blockIdx.x;

  // ---- stage weights into LDS (one-time per block) ----
  for (int idx = tid; idx < 128 * 80; idx += TPB) {
    int j = idx / 80, i = idx - j * 80;
    sm[W0_OFF + j * W0_STR + i] = W0g[idx];
  }
  for (int idx = tid; idx < 128 * 128; idx += TPB) {
    int j = idx >> 7, i = idx & 127;
    sm[W1_OFF + j * W1_STR + i] = W1g[idx];
  }
  for (int idx = tid; idx < 64 * 128; idx += TPB) {
    int j = idx >> 7, i = idx & 127;
    sm[W2_OFF + j * W2_STR + i] = W2g[idx];
  }
  if (tid < 128) { sm[B0_OFF + tid] = b0g[tid]; sm[B1_OFF + tid] = b1g[tid]; }
  if (tid < 64)  { sm[B2_OFF + tid] = b2g[tid]; }
  if (tid < 64) {           // u occupies z[64..79] for 4 elements
    int e = tid >> 4, c = tid & 15;
    sm[Z_OFF + e * Z_STR + 64 + c] = u[(blk * 4 + e) * 16 + c];
  }

  const int wv   = tid >> 6;        // wave 0..1
  const int lane = tid & 63;        // state dim / feature base
  const int eA = 2 * wv, eB = 2 * wv + 1;
  const int geA = blk * 4 + eA, geB = blk * 4 + eB;

  float yA = x0[geA * 64 + lane];
  float yB = x0[geB * 64 + lane];
  const float t1  = *t1p;
  const float t1m = t1 - 1e-12f;    // matches XLA: f32(1.0 - 1e-12) == 1.0f
  float tA = *t0p, tB = tA;
  float dtA = (float)(60.0 * (1.0 / 3600.0)), dtB = dtA;
  int nstA = 0, nstB = 0;

  // DOPRI5 coefficients (f64 literals rounded to f32, as XLA does)
  constexpr float cA21 = (float)0.161;
  constexpr float cA31 = (float)-0.008480655492356989, cA32 = (float)0.335480655492357;
  constexpr float cA41 = (float)2.8971530571054935,  cA42 = (float)-6.359448489975075,  cA43 = (float)4.3622954328695815;
  constexpr float cA51 = (float)5.325864828439257,   cA52 = (float)-11.748883564062828, cA53 = (float)7.4955393428898365, cA54 = (float)-0.09249506636175525;
  constexpr float cA61 = (float)5.86145544294642,    cA62 = (float)-12.92096931784711,  cA63 = (float)8.159367898576159,  cA64 = (float)-0.071584973281401, cA65 = (float)-0.028269050394068383;
  constexpr float cB1 = (float)0.09646076681806523,  cB2 = (float)0.01, cB3 = (float)0.4798896504144996;
  constexpr float cB4 = (float)1.379008574103742,    cB5 = (float)-3.290069515436081, cB6 = (float)2.324710524099774;
  constexpr float cE1 = (float)-0.001780011052226,   cE2 = (float)-0.000816434459657, cE3 = (float)0.007880878010262;
  constexpr float cE4 = (float)-0.144711007173263,   cE5 = (float)0.582357165452555,  cE6 = (float)-0.458082105929187;
  constexpr float cE7 = (float)(-1.0 / 66.0);

  __syncthreads();   // the ONLY barrier: weights/u staged

  float* zA  = sm + Z_OFF + eA * Z_STR;
  float* zB  = sm + Z_OFF + eB * Z_STR;
  float* hA1 = sm + HA_OFF + eA * H_STR;
  float* hB1 = sm + HA_OFF + eB * H_STR;
  float* hA2 = sm + HB_OFF + eA * H_STR;
  float* hB2 = sm + HB_OFF + eB * H_STR;

  for (int it = 0; it < 128; ++it) {
    const bool doneA = (tA >= t1m);
    const bool doneB = (tB >= t1m);
    if (doneA && doneB) break;      // wave-uniform (t is lane-uniform)

    const float dA = fminf(dtA, t1 - tA);
    const float dB = fminf(dtB, t1 - tB);

    float k1A, k1B, k2A, k2B, k3A, k3B, k4A, k4B, k5A, k5B, k6A, k6B, k7A, k7B;

    zA[lane] = yA;  zB[lane] = yB;
    eval_f2(sm, hA1, hB1, hA2, hB2, zA, zB, lane, k1A, k1B);

    zA[lane] = yA + dA * (cA21 * k1A);
    zB[lane] = yB + dB * (cA21 * k1B);
    eval_f2(sm, hA1, hB1, hA2, hB2, zA, zB, lane, k2A, k2B);

    zA[lane] = yA + dA * (cA31 * k1A + cA32 * k2A);
    zB[lane] = yB + dB * (cA31 * k1B + cA32 * k2B);
    eval_f2(sm, hA1, hB1, hA2, hB2, zA, zB, lane, k3A, k3B);

    zA[lane] = yA + dA * (cA41 * k1A + cA42 * k2A + cA43 * k3A);
    zB[lane] = yB + dB * (cA41 * k1B + cA42 * k2B + cA43 * k3B);
    eval_f2(sm, hA1, hB1, hA2, hB2, zA, zB, lane, k4A, k4B);

    zA[lane] = yA + dA * (cA51 * k1A + cA52 * k2A + cA53 * k3A + cA54 * k4A);
    zB[lane] = yB + dB * (cA51 * k1B + cA52 * k2B + cA53 * k3B + cA54 * k4B);
    eval_f2(sm, hA1, hB1, hA2, hB2, zA, zB, lane, k5A, k5B);

    zA[lane] = yA + dA * (cA61 * k1A + cA62 * k2A + cA63 * k3A + cA64 * k4A + cA65 * k5A);
    zB[lane] = yB + dB * (cA61 * k1B + cA62 * k2B + cA63 * k3B + cA64 * k4B + cA65 * k5B);
    eval_f2(sm, hA1, hB1, hA2, hB2, zA, zB, lane, k6A, k6B);

    const float y5A = yA + dA * (cB1 * k1A + cB2 * k2A + cB3 * k3A + cB4 * k4A + cB5 * k5A + cB6 * k6A);
    const float y5B = yB + dB * (cB1 * k1B + cB2 * k2B + cB3 * k3B + cB4 * k4B + cB5 * k5B + cB6 * k6B);
    zA[lane] = y5A;  zB[lane] = y5B;
    eval_f2(sm, hA1, hB1, hA2, hB2, zA, zB, lane, k7A, k7B);

    const float errA = dA * (cE1 * k1A + cE2 * k2A + cE3 * k3A + cE4 * k4A + cE5 * k5A + cE6 * k6A + cE7 * k7A);
    const float errB = dB * (cE1 * k1B + cE2 * k2B + cE3 * k3B + cE4 * k4B + cE5 * k5B + cE6 * k6B + cE7 * k7B);
    const float scA = 1.4e-8f + 1.4e-8f * fmaxf(fabsf(yA), fabsf(y5A));
    const float scB = 1.4e-8f + 1.4e-8f * fmaxf(fabsf(yB), fabsf(y5B));
    const float rA = errA / scA;
    const float rB = errB / scB;
    float s2A = rA * rA;
    float s2B = rB * rB;
#pragma unroll
    for (int m = 1; m < 64; m <<= 1) {
      s2A += __shfl_xor(s2A, m);
      s2B += __shfl_xor(s2B, m);
    }
    const float enA = sqrtf(s2A * (1.0f / 64.0f));
    const float enB = sqrtf(s2B * (1.0f / 64.0f));

    float facA = 0.9f * powf(fmaxf(enA, 1e-16f), -0.2f);
    float facB = 0.9f * powf(fmaxf(enB, 1e-16f), -0.2f);
    facA = fminf(10.0f, fmaxf(0.1f, facA));
    facB = fminf(10.0f, fmaxf(0.1f, facB));

    const bool stepA = (enA <= 1.0f) && !doneA;
    const bool stepB = (enB <= 1.0f) && !doneB;
    if (stepA) { tA = tA + dA; yA = y5A; }
    if (stepB) { tB = tB + dB; yB = y5B; }
    if (!doneA) dtA = dA * facA;
    if (!doneB) dtB = dB * facB;
    nstA += doneA ? 0 : 1;
    nstB += doneB ? 0 : 1;
  }

  // ---- outputs: y (B x 64) then nsteps (B) as float ----
  out[geA * 64 + lane] = yA;
  out[geB * 64 + lane] = yB;
  if (lane == 0) {
    out[B * 64 + geA] = (float)nstA;
    out[B * 64 + geB] = (float)nstB;
  }
}

extern "C" void kernel_launch(void* const* d_in, const int* in_sizes, int n_in,
                              void* d_out, int out_size, void* d_ws, size_t ws_size,
                              hipStream_t stream) {
  const float* x0 = (const float*)d_in[0];
  const float* u  = (const float*)d_in[1];
  const float* t0 = (const float*)d_in[2];
  const float* t1 = (const float*)d_in[3];
  const float* W0 = (const float*)d_in[4];
  const float* b0 = (const float*)d_in[5];
  const float* W1 = (const float*)d_in[6];
  const float* b1 = (const float*)d_in[7];
  const float* W2 = (const float*)d_in[8];
  const float* b2 = (const float*)d_in[9];
  float* out = (float*)d_out;

  const int B = in_sizes[0] / 64;   // 1024
  const int nblk = B / 4;           // 4 elements per block (2 per wave), 256 blocks

  (void)hipFuncSetAttribute((const void*)ode_solver,
                            hipFuncAttributeMaxDynamicSharedMemorySize, SM_BYTES);
  ode_solver<<<nblk, TPB, SM_BYTES, stream>>>(x0, u, t0, t1, W0, b0, W1, b1, W2, b2, out, B);
}

// Round 10
// 4900.891 us; speedup vs baseline: 1.9477x; 1.2751x over previous
//
#include <hip/hip_runtime.h>
#include <math.h>

#define TPB 256

// ---- LDS layout (float word offsets) ----
// Weight rows padded: stride 84 (mod 32 = 20) and 132 (mod 32 = 4) are
// bank-bijective per 8-lane phase -> conflict-free ds_read_b128 (proven R3/R4).
#define W0_OFF 0        // 128 rows x 84 (80 used)
#define W0_STR 84
#define W1_OFF 10752    // 128 rows x 132 (128 used)
#define W1_STR 132
#define W2_OFF 27648    // 64 rows x 132 (128 used)
#define W2_STR 132
#define B0_OFF 36096    // 128
#define B1_OFF 36224    // 128
#define B2_OFF 36352    // 64
#define Z_OFF  36416    // 4 x 84   (z = [y(64), u(16)])
#define Z_STR  84
#define HA_OFF 36752    // 4 x 128  h1
#define HB_OFF 37264    // 4 x 128  h2
#define H_STR  128
#define T_OFF  37776    // 4 (published t per element)
#define SM_WORDS 37780  // 151.1 KB
#define SM_BYTES (SM_WORDS * 4)

__device__ __forceinline__ float4 ld4(const float* p) {
  return *reinterpret_cast<const float4*>(p);
}

// One MLP eval, S=4 weight sharing:
// L1/L2: thread (wave wv, lane l) computes feature j = 32*wv + (l&31) for
//   element pair p = l>>5 (2 chains). Lanes l and l+32 read the SAME weight
//   row -> each wave-instr moves only 512B; 4 waves cover 128 feats x 4 els.
// L3: wave wv computes element wv, dim = lane -> k lands in the solver
//   wave's register directly; h2 read is wave-uniform broadcast.
// Every output is one ascending fmaf chain from its bias (bit-exact, same
// order as the R3/R4 absmax=0.0 kernels). Chunked loops (#pragma unroll 1)
// cap in-flight loads (R5 spill lesson).
// Internal barriers: after h1 writes (L2 reads all), after h2 writes (L3
// reads all). Caller provides the barrier between z writes and L1.
__device__ __forceinline__ float eval_f(float* __restrict__ sm, int wv, int lane) {
  const int j = 32 * wv + (lane & 31);
  const int p = lane >> 5;

  // ---- L1: h1 = tanh(W0 z + b0), fan_in 80 ----
  {
    float a0 = sm[B0_OFF + j];
    float a1 = a0;
    const float* wr = sm + W0_OFF + j * W0_STR;
    const float* z0 = sm + Z_OFF + (2 * p) * Z_STR;
    const float* z1 = sm + Z_OFF + (2 * p + 1) * Z_STR;
#pragma unroll 1
    for (int c = 0; c < 4; ++c) {
#pragma unroll
      for (int q = 0; q < 5; ++q) {
        const int i4 = c * 5 + q;
        float4 w  = ld4(wr + i4 * 4);
        float4 za = ld4(z0 + i4 * 4);
        float4 zb = ld4(z1 + i4 * 4);
        a0 = fmaf(w.x, za.x, a0); a0 = fmaf(w.y, za.y, a0);
        a0 = fmaf(w.z, za.z, a0); a0 = fmaf(w.w, za.w, a0);
        a1 = fmaf(w.x, zb.x, a1); a1 = fmaf(w.y, zb.y, a1);
        a1 = fmaf(w.z, zb.z, a1); a1 = fmaf(w.w, zb.w, a1);
      }
    }
    sm[HA_OFF + (2 * p) * H_STR + j]     = tanhf(a0);
    sm[HA_OFF + (2 * p + 1) * H_STR + j] = tanhf(a1);
  }
  __syncthreads();

  // ---- L2: h2 = tanh(W1 h1 + b1), fan_in 128 ----
  {
    float a0 = sm[B1_OFF + j];
    float a1 = a0;
    const float* wr = sm + W1_OFF + j * W1_STR;
    const float* z0 = sm + HA_OFF + (2 * p) * H_STR;
    const float* z1 = sm + HA_OFF + (2 * p + 1) * H_STR;
#pragma unroll 1
    for (int c = 0; c < 4; ++c) {
#pragma unroll
      for (int q = 0; q < 8; ++q) {
        const int i4 = c * 8 + q;
        float4 w  = ld4(wr + i4 * 4);
        float4 za = ld4(z0 + i4 * 4);
        float4 zb = ld4(z1 + i4 * 4);
        a0 = fmaf(w.x, za.x, a0); a0 = fmaf(w.y, za.y, a0);
        a0 = fmaf(w.z, za.z, a0); a0 = fmaf(w.w, za.w, a0);
        a1 = fmaf(w.x, zb.x, a1); a1 = fmaf(w.y, zb.y, a1);
        a1 = fmaf(w.z, zb.z, a1); a1 = fmaf(w.w, zb.w, a1);
      }
    }
    sm[HB_OFF + (2 * p) * H_STR + j]     = tanhf(a0);
    sm[HB_OFF + (2 * p + 1) * H_STR + j] = tanhf(a1);
  }
  __syncthreads();

  // ---- L3: k[el=wv][dim=lane] = W2 h2 + b2 (no tanh) ----
  float a = sm[B2_OFF + lane];
  const float* wr = sm + W2_OFF + lane * W2_STR;
  const float* z  = sm + HB_OFF + wv * H_STR;   // wave-uniform broadcast
#pragma unroll 1
  for (int c = 0; c < 4; ++c) {
#pragma unroll
    for (int q = 0; q < 8; ++q) {
      const int i4 = c * 8 + q;
      float4 w  = ld4(wr + i4 * 4);
      float4 zz = ld4(z + i4 * 4);
      a = fmaf(w.x, zz.x, a); a = fmaf(w.y, zz.y, a);
      a = fmaf(w.z, zz.z, a); a = fmaf(w.w, zz.w, a);
    }
  }
  return a;
  // NOTE: no barrier here. Next z-write (different buffer) + its barrier
  // precede any L1 read; h2 is not rewritten until after the next L1 barrier.
}

__global__ __launch_bounds__(TPB, 1)
void ode_solver(const float* __restrict__ x0, const float* __restrict__ u,
                const float* __restrict__ t0p, const float* __restrict__ t1p,
                const float* __restrict__ W0g, const float* __restrict__ b0g,
                const float* __restrict__ W1g, const float* __restrict__ b1g,
                const float* __restrict__ W2g, const float* __restrict__ b2g,
                float* __restrict__ out, int B)
{
  extern __shared__ float sm[];
  const int tid = threadIdx.x;
  const int blk = blockIdx.x;

  // ---- stage weights into LDS (one-time per block) ----
  for (int idx = tid; idx < 128 * 80; idx += TPB) {
    int j = idx / 80, i = idx - j * 80;
    sm[W0_OFF + j * W0_STR + i] = W0g[idx];
  }
  for (int idx = tid; idx < 128 * 128; idx += TPB) {
    int j = idx >> 7, i = idx & 127;
    sm[W1_OFF + j * W1_STR + i] = W1g[idx];
  }
  for (int idx = tid; idx < 64 * 128; idx += TPB) {
    int j = idx >> 7, i = idx & 127;
    sm[W2_OFF + j * W2_STR + i] = W2g[idx];
  }
  if (tid < 128) { sm[B0_OFF + tid] = b0g[tid]; sm[B1_OFF + tid] = b1g[tid]; }
  if (tid < 64)  { sm[B2_OFF + tid] = b2g[tid]; }
  if (tid < 64) {           // u occupies z[64..79], constant for whole solve
    int e = tid >> 4, c = tid & 15;
    sm[Z_OFF + e * Z_STR + 64 + c] = u[(blk * 4 + e) * 16 + c];
  }

  const int wv   = tid >> 6;        // wave 0..3 == element owned
  const int lane = tid & 63;        // state dim
  const int ge = blk * 4 + wv;      // global element

  float y = x0[ge * 64 + lane];
  const float t1  = *t1p;
  const float t1m = t1 - 1e-12f;    // matches XLA: f32(1.0 - 1e-12) == 1.0f
  float tcur = *t0p;
  float dt   = (float)(60.0 * (1.0 / 3600.0));
  int nst = 0;

  // DOPRI5 coefficients (f64 literals rounded to f32, as XLA does)
  constexpr float cA21 = (float)0.161;
  constexpr float cA31 = (float)-0.008480655492356989, cA32 = (float)0.335480655492357;
  constexpr float cA41 = (float)2.8971530571054935,  cA42 = (float)-6.359448489975075,  cA43 = (float)4.3622954328695815;
  constexpr float cA51 = (float)5.325864828439257,   cA52 = (float)-11.748883564062828, cA53 = (float)7.4955393428898365, cA54 = (float)-0.09249506636175525;
  constexpr float cA61 = (float)5.86145544294642,    cA62 = (float)-12.92096931784711,  cA63 = (float)8.159367898576159,  cA64 = (float)-0.071584973281401, cA65 = (float)-0.028269050394068383;
  constexpr float cB1 = (float)0.09646076681806523,  cB2 = (float)0.01, cB3 = (float)0.4798896504144996;
  constexpr float cB4 = (float)1.379008574103742,    cB5 = (float)-3.290069515436081, cB6 = (float)2.324710524099774;
  constexpr float cE1 = (float)-0.001780011052226,   cE2 = (float)-0.000816434459657, cE3 = (float)0.007880878010262;
  constexpr float cE4 = (float)-0.144711007173263,   cE5 = (float)0.582357165452555,  cE6 = (float)-0.458082105929187;
  constexpr float cE7 = (float)(-1.0 / 66.0);

  __syncthreads();

  float* zrow = sm + Z_OFF + wv * Z_STR;

  for (int it = 0; it < 128; ++it) {
    // publish stage-1 input (z = y) and current t
    zrow[lane] = y;
    if (lane == 0) sm[T_OFF + wv] = tcur;
    __syncthreads();
    const bool alldone = (sm[T_OFF + 0] >= t1m) && (sm[T_OFF + 1] >= t1m) &&
                         (sm[T_OFF + 2] >= t1m) && (sm[T_OFF + 3] >= t1m);
    if (alldone) break;          // uniform across block

    const bool  done = (tcur >= t1m);
    const float dt_c = fminf(dt, t1 - tcur);
    const float d    = dt_c;

    const float k1 = eval_f(sm, wv, lane);
    zrow[lane] = y + d * (cA21 * k1);
    __syncthreads();
    const float k2 = eval_f(sm, wv, lane);
    zrow[lane] = y + d * (cA31 * k1 + cA32 * k2);
    __syncthreads();
    const float k3 = eval_f(sm, wv, lane);
    zrow[lane] = y + d * (cA41 * k1 + cA42 * k2 + cA43 * k3);
    __syncthreads();
    const float k4 = eval_f(sm, wv, lane);
    zrow[lane] = y + d * (cA51 * k1 + cA52 * k2 + cA53 * k3 + cA54 * k4);
    __syncthreads();
    const float k5 = eval_f(sm, wv, lane);
    zrow[lane] = y + d * (cA61 * k1 + cA62 * k2 + cA63 * k3 + cA64 * k4 + cA65 * k5);
    __syncthreads();
    const float k6 = eval_f(sm, wv, lane);
    const float y5v = y + d * (cB1 * k1 + cB2 * k2 + cB3 * k3 + cB4 * k4 + cB5 * k5 + cB6 * k6);
    zrow[lane] = y5v;
    __syncthreads();
    const float k7 = eval_f(sm, wv, lane);

    const float err = d * (cE1 * k1 + cE2 * k2 + cE3 * k3 + cE4 * k4 + cE5 * k5 + cE6 * k6 + cE7 * k7);
    const float sc  = 1.4e-8f + 1.4e-8f * fmaxf(fabsf(y), fabsf(y5v));
    const float r   = err / sc;
    float s2 = r * r;
#pragma unroll
    for (int m = 1; m < 64; m <<= 1) s2 += __shfl_xor(s2, m);
    const float en = sqrtf(s2 * (1.0f / 64.0f));

    const bool accept = (en <= 1.0f);
    float fac = 0.9f * powf(fmaxf(en, 1e-16f), -0.2f);
    fac = fminf(10.0f, fmaxf(0.1f, fac));
    const bool step = accept && !done;
    if (step) { tcur = tcur + dt_c; y = y5v; }
    if (!done) dt = dt_c * fac;
    nst += done ? 0 : 1;
  }

  // ---- outputs: y (B x 64) then nsteps (B) as float ----
  out[ge * 64 + lane] = y;
  if (lane == 0) out[B * 64 + ge] = (float)nst;
}

extern "C" void kernel_launch(void* const* d_in, const int* in_sizes, int n_in,
                              void* d_out, int out_size, void* d_ws, size_t ws_size,
                              hipStream_t stream) {
  const float* x0 = (const float*)d_in[0];
  const float* u  = (const float*)d_in[1];
  const float* t0 = (const float*)d_in[2];
  const float* t1 = (const float*)d_in[3];
  const float* W0 = (const float*)d_in[4];
  const float* b0 = (const float*)d_in[5];
  const float* W1 = (const float*)d_in[6];
  const float* b1 = (const float*)d_in[7];
  const float* W2 = (const float*)d_in[8];
  const float* b2 = (const float*)d_in[9];
  float* out = (float*)d_out;

  const int B = in_sizes[0] / 64;   // 1024
  const int nblk = B / 4;           // 4 elements per block, 256 blocks

  (void)hipFuncSetAttribute((const void*)ode_solver,
                            hipFuncAttributeMaxDynamicSharedMemorySize, SM_BYTES);
  ode_solver<<<nblk, TPB, SM_BYTES, stream>>>(x0, u, t0, t1, W0, b0, W1, b1, W2, b2, out, B);
}

// Round 12
// 2956.551 us; speedup vs baseline: 3.2286x; 1.6576x over previous
//
#include <hip/hip_runtime.h>
#include <math.h>

#define TPB 256

// ---- LDS layout (float word offsets) ----
// Weight rows padded: stride 84 (mod 32 = 20) and 132 (mod 32 = 4) are
// bank-bijective per 8-lane phase -> conflict-free ds_read_b128 (proven R3/R4).
#define W0_OFF 0        // 128 rows x 84 (80 used)
#define W0_STR 84
#define W1_OFF 10752    // 128 rows x 132 (128 used)
#define W1_STR 132
#define W2_OFF 27648    // 64 rows x 132 (128 used)
#define W2_STR 132
#define B0_OFF 36096    // 128
#define B1_OFF 36224    // 128
#define B2_OFF 36352    // 64
#define Z_OFF  36416    // 4 x 84   (z = [y(64), u(16)]) — wave-private rows
#define Z_STR  84
#define HA_OFF 36752    // 4 x 128  h1 — wave-private
#define HB_OFF 37264    // 4 x 128  h2 — wave-private
#define H_STR  128
#define SM_WORDS 37776  // 151.1 KB
#define SM_BYTES (SM_WORDS * 4)

__device__ __forceinline__ float4 ld4(const float* p) {
  return *reinterpret_cast<const float4*>(p);
}

// MLP eval for THIS WAVE's private element. No __syncthreads anywhere:
// z/h rows are wave-private (within-wave ds_write->ds_read ordered by
// lgkmcnt), weights are static after staging. All layer loops are FULLY
// unrolled straight-line (R3-proven shape, <=60 float4 in flight per
// section; the R8/R10 "#pragma unroll 1" chunking is the proven
// regression and is gone). Long layers are two back-to-back straight-line
// halves in ONE basic block, ascending i4 order -> bit-exact chains, and
// the scheduler may hoist half-2 / next-layer WEIGHT loads into the
// current FMA tail (no barrier stops it).
__device__ __forceinline__ float eval_f(const float* __restrict__ sm,
                                        float* __restrict__ zrow,
                                        float* __restrict__ h1row,
                                        float* __restrict__ h2row,
                                        int lane)
{
  // ---- L1: h1 = tanh(W0 z + b0), fan_in 80; feats lane, lane+64 ----
  {
    float a0 = sm[B0_OFF + lane];
    float a1 = sm[B0_OFF + lane + 64];
    const float* w0a = sm + W0_OFF + lane * W0_STR;
    const float* w0b = sm + W0_OFF + (lane + 64) * W0_STR;
#pragma unroll
    for (int i4 = 0; i4 < 20; ++i4) {
      float4 wa = ld4(w0a + i4 * 4);
      float4 wb = ld4(w0b + i4 * 4);
      float4 zz = ld4(zrow + i4 * 4);
      a0 = fmaf(wa.x, zz.x, a0); a0 = fmaf(wa.y, zz.y, a0);
      a0 = fmaf(wa.z, zz.z, a0); a0 = fmaf(wa.w, zz.w, a0);
      a1 = fmaf(wb.x, zz.x, a1); a1 = fmaf(wb.y, zz.y, a1);
      a1 = fmaf(wb.z, zz.z, a1); a1 = fmaf(wb.w, zz.w, a1);
    }
    h1row[lane]      = tanhf(a0);
    h1row[lane + 64] = tanhf(a1);
  }

  // ---- L2: h2 = tanh(W1 h1 + b1), fan_in 128; two straight halves ----
  {
    float a0 = sm[B1_OFF + lane];
    float a1 = sm[B1_OFF + lane + 64];
    const float* w1a = sm + W1_OFF + lane * W1_STR;
    const float* w1b = sm + W1_OFF + (lane + 64) * W1_STR;
#pragma unroll
    for (int i4 = 0; i4 < 16; ++i4) {
      float4 wa = ld4(w1a + i4 * 4);
      float4 wb = ld4(w1b + i4 * 4);
      float4 zz = ld4(h1row + i4 * 4);
      a0 = fmaf(wa.x, zz.x, a0); a0 = fmaf(wa.y, zz.y, a0);
      a0 = fmaf(wa.z, zz.z, a0); a0 = fmaf(wa.w, zz.w, a0);
      a1 = fmaf(wb.x, zz.x, a1); a1 = fmaf(wb.y, zz.y, a1);
      a1 = fmaf(wb.z, zz.z, a1); a1 = fmaf(wb.w, zz.w, a1);
    }
#pragma unroll
    for (int i4 = 16; i4 < 32; ++i4) {
      float4 wa = ld4(w1a + i4 * 4);
      float4 wb = ld4(w1b + i4 * 4);
      float4 zz = ld4(h1row + i4 * 4);
      a0 = fmaf(wa.x, zz.x, a0); a0 = fmaf(wa.y, zz.y, a0);
      a0 = fmaf(wa.z, zz.z, a0); a0 = fmaf(wa.w, zz.w, a0);
      a1 = fmaf(wb.x, zz.x, a1); a1 = fmaf(wb.y, zz.y, a1);
      a1 = fmaf(wb.z, zz.z, a1); a1 = fmaf(wb.w, zz.w, a1);
    }
    h2row[lane]      = tanhf(a0);
    h2row[lane + 64] = tanhf(a1);
  }

  // ---- L3: k[dim=lane] = W2 h2 + b2 (no tanh); two straight halves ----
  {
    float a = sm[B2_OFF + lane];
    const float* w2 = sm + W2_OFF + lane * W2_STR;
#pragma unroll
    for (int i4 = 0; i4 < 16; ++i4) {
      float4 w  = ld4(w2 + i4 * 4);
      float4 zz = ld4(h2row + i4 * 4);
      a = fmaf(w.x, zz.x, a); a = fmaf(w.y, zz.y, a);
      a = fmaf(w.z, zz.z, a); a = fmaf(w.w, zz.w, a);
    }
#pragma unroll
    for (int i4 = 16; i4 < 32; ++i4) {
      float4 w  = ld4(w2 + i4 * 4);
      float4 zz = ld4(h2row + i4 * 4);
      a = fmaf(w.x, zz.x, a); a = fmaf(w.y, zz.y, a);
      a = fmaf(w.z, zz.z, a); a = fmaf(w.w, zz.w, a);
    }
    return a;
  }
}

__global__ __launch_bounds__(TPB, 1)
void ode_solver(const float* __restrict__ x0, const float* __restrict__ u,
                const float* __restrict__ t0p, const float* __restrict__ t1p,
                const float* __restrict__ W0g, const float* __restrict__ b0g,
                const float* __restrict__ W1g, const float* __restrict__ b1g,
                const float* __restrict__ W2g, const float* __restrict__ b2g,
                float* __restrict__ out, int B)
{
  extern __shared__ float sm[];
  const int tid = threadIdx.x;
  const int blk = blockIdx.x;

  // ---- stage weights into LDS (one-time per block) ----
  for (int idx = tid; idx < 128 * 80; idx += TPB) {
    int j = idx / 80, i = idx - j * 80;
    sm[W0_OFF + j * W0_STR + i] = W0g[idx];
  }
  for (int idx = tid; idx < 128 * 128; idx += TPB) {
    int j = idx >> 7, i = idx & 127;
    sm[W1_OFF + j * W1_STR + i] = W1g[idx];
  }
  for (int idx = tid; idx < 64 * 128; idx += TPB) {
    int j = idx >> 7, i = idx & 127;
    sm[W2_OFF + j * W2_STR + i] = W2g[idx];
  }
  if (tid < 128) { sm[B0_OFF + tid] = b0g[tid]; sm[B1_OFF + tid] = b1g[tid]; }
  if (tid < 64)  { sm[B2_OFF + tid] = b2g[tid]; }
  if (tid < 64) {           // u occupies z[64..79], constant for whole solve
    int e = tid >> 4, c = tid & 15;
    sm[Z_OFF + e * Z_STR + 64 + c] = u[(blk * 4 + e) * 16 + c];
  }

  const int wv   = tid >> 6;        // wave 0..3 == private element
  const int lane = tid & 63;        // state dim / feature base
  const int ge = blk * 4 + wv;      // global element

  float y = x0[ge * 64 + lane];
  const float t1  = *t1p;
  const float t1m = t1 - 1e-12f;    // matches XLA: f32(1.0 - 1e-12) == 1.0f
  float tcur = *t0p;
  float dt   = (float)(60.0 * (1.0 / 3600.0));
  int nst = 0;

  // DOPRI5 coefficients (f64 literals rounded to f32, as XLA does)
  constexpr float cA21 = (float)0.161;
  constexpr float cA31 = (float)-0.008480655492356989, cA32 = (float)0.335480655492357;
  constexpr float cA41 = (float)2.8971530571054935,  cA42 = (float)-6.359448489975075,  cA43 = (float)4.3622954328695815;
  constexpr float cA51 = (float)5.325864828439257,   cA52 = (float)-11.748883564062828, cA53 = (float)7.4955393428898365, cA54 = (float)-0.09249506636175525;
  constexpr float cA61 = (float)5.86145544294642,    cA62 = (float)-12.92096931784711,  cA63 = (float)8.159367898576159,  cA64 = (float)-0.071584973281401, cA65 = (float)-0.028269050394068383;
  constexpr float cB1 = (float)0.09646076681806523,  cB2 = (float)0.01, cB3 = (float)0.4798896504144996;
  constexpr float cB4 = (float)1.379008574103742,    cB5 = (float)-3.290069515436081, cB6 = (float)2.324710524099774;
  constexpr float cE1 = (float)-0.001780011052226,   cE2 = (float)-0.000816434459657, cE3 = (float)0.007880878010262;
  constexpr float cE4 = (float)-0.144711007173263,   cE5 = (float)0.582357165452555,  cE6 = (float)-0.458082105929187;
  constexpr float cE7 = (float)(-1.0 / 66.0);

  __syncthreads();   // the ONLY barrier: weights/u staged

  float* zrow  = sm + Z_OFF + wv * Z_STR;
  float* h1row = sm + HA_OFF + wv * H_STR;
  float* h2row = sm + HB_OFF + wv * H_STR;

  for (int it = 0; it < 128; ++it) {
    const bool done = (tcur >= t1m);
    if (done) break;                 // wave-uniform (t is lane-uniform)

    const float dt_c = fminf(dt, t1 - tcur);
    const float d    = dt_c;

    zrow[lane] = y;
    const float k1 = eval_f(sm, zrow, h1row, h2row, lane);
    zrow[lane] = y + d * (cA21 * k1);
    const float k2 = eval_f(sm, zrow, h1row, h2row, lane);
    zrow[lane] = y + d * (cA31 * k1 + cA32 * k2);
    const float k3 = eval_f(sm, zrow, h1row, h2row, lane);
    zrow[lane] = y + d * (cA41 * k1 + cA42 * k2 + cA43 * k3);
    const float k4 = eval_f(sm, zrow, h1row, h2row, lane);
    zrow[lane] = y + d * (cA51 * k1 + cA52 * k2 + cA53 * k3 + cA54 * k4);
    const float k5 = eval_f(sm, zrow, h1row, h2row, lane);
    zrow[lane] = y + d * (cA61 * k1 + cA62 * k2 + cA63 * k3 + cA64 * k4 + cA65 * k5);
    const float k6 = eval_f(sm, zrow, h1row, h2row, lane);
    const float y5v = y + d * (cB1 * k1 + cB2 * k2 + cB3 * k3 + cB4 * k4 + cB5 * k5 + cB6 * k6);
    zrow[lane] = y5v;
    const float k7 = eval_f(sm, zrow, h1row, h2row, lane);

    const float err = d * (cE1 * k1 + cE2 * k2 + cE3 * k3 + cE4 * k4 + cE5 * k5 + cE6 * k6 + cE7 * k7);
    const float sc  = 1.4e-8f + 1.4e-8f * fmaxf(fabsf(y), fabsf(y5v));
    const float r   = err / sc;
    float s2 = r * r;
#pragma unroll
    for (int m = 1; m < 64; m <<= 1) s2 += __shfl_xor(s2, m);
    const float en = sqrtf(s2 * (1.0f / 64.0f));

    const bool accept = (en <= 1.0f);
    float fac = 0.9f * powf(fmaxf(en, 1e-16f), -0.2f);
    fac = fminf(10.0f, fmaxf(0.1f, fac));
    if (accept) { tcur = tcur + dt_c; y = y5v; }
    dt = dt_c * fac;
    nst += 1;
  }

  // ---- outputs: y (B x 64) then nsteps (B) as float ----
  out[ge * 64 + lane] = y;
  if (lane == 0) out[B * 64 + ge] = (float)nst;
}

extern "C" void kernel_launch(void* const* d_in, const int* in_sizes, int n_in,
                              void* d_out, int out_size, void* d_ws, size_t ws_size,
                              hipStream_t stream) {
  const float* x0 = (const float*)d_in[0];
  const float* u  = (const float*)d_in[1];
  const float* t0 = (const float*)d_in[2];
  const float* t1 = (const float*)d_in[3];
  const float* W0 = (const float*)d_in[4];
  const float* b0 = (const float*)d_in[5];
  const float* W1 = (const float*)d_in[6];
  const float* b1 = (const float*)d_in[7];
  const float* W2 = (const float*)d_in[8];
  const float* b2 = (const float*)d_in[9];
  float* out = (float*)d_out;

  const int B = in_sizes[0] / 64;   // 1024
  const int nblk = B / 4;           // 4 elements per block (1 per wave), 256 blocks

  (void)hipFuncSetAttribute((const void*)ode_solver,
                            hipFuncAttributeMaxDynamicSharedMemorySize, SM_BYTES);
  ode_solver<<<nblk, TPB, SM_BYTES, stream>>>(x0, u, t0, t1, W0, b0, W1, b1, W2, b2, out, B);
}